// Round 9
// baseline (518.240 us; speedup 1.0000x reference)
//
#include <hip/hip_runtime.h>

typedef __attribute__((ext_vector_type(4))) float f32x4;
typedef __attribute__((ext_vector_type(8))) short bf16x8;

#define MFMA16(a, b, c) __builtin_amdgcn_mfma_f32_16x16x32_bf16((a), (b), (c), 0, 0, 0)
#define LOG2E 1.44269504088896340736f

static __device__ __forceinline__ float bf2f(short u) {
  unsigned x = ((unsigned)(unsigned short)u) << 16;
  return __builtin_bit_cast(float, x);
}
static __device__ __forceinline__ short f2bf(float f) {
  unsigned u = __builtin_bit_cast(unsigned, f);
  u += 0x7fffu + ((u >> 16) & 1u);
  return (short)(u >> 16);
}
// global -> LDS direct DMA, 16B per lane (guide §5); source pre-swizzled.
static __device__ __forceinline__ void gll16(const void* g, void* l) {
  __builtin_amdgcn_global_load_lds(
      (const __attribute__((address_space(1))) unsigned*)(unsigned long long)g,
      (__attribute__((address_space(3))) unsigned*)(unsigned)(unsigned long long)l,
      16, 0, 0);
}

// ---------------- f32 -> bf16 conversion (vectorized, G13) ----------------
__global__ void __launch_bounds__(256) cvt_kernel(const float* __restrict__ src,
                                                  short* __restrict__ dst,
                                                  long long n) {
  long long i = ((long long)blockIdx.x * 256 + threadIdx.x) * 8;
  const long long stride = (long long)gridDim.x * 256 * 8;
  for (; i < n; i += stride) {
    f32x4 a = *(const f32x4*)(src + i);
    f32x4 b = *(const f32x4*)(src + i + 4);
    bf16x8 o;
    o[0] = f2bf(a[0]); o[1] = f2bf(a[1]); o[2] = f2bf(a[2]); o[3] = f2bf(a[3]);
    o[4] = f2bf(b[0]); o[5] = f2bf(b[1]); o[6] = f2bf(b[2]); o[7] = f2bf(b[3]);
    *(bf16x8*)(dst + i) = o;
  }
}

// ---------------- RoPE cos/sin table: [2048][64] ----------------
__global__ void rope_table(const int* __restrict__ pos, float* __restrict__ ctab,
                           float* __restrict__ stab) {
  const int s = blockIdx.x;
  const int i = threadIdx.x;  // 0..63
  const float p = (float)pos[s];
  const float ang = p * exp2f(-(float)i * 0.3114307588956902f);
  ctab[s * 64 + i] = cosf(ang);
  stab[s * 64 + i] = sinf(ang);
}

// ---- stream-K partial-sum helpers (QKV: 36 units/block, 56 units/tile) ----
// Block bid = row + 8*j (row = M-tile, j = 0..27 within XCD row). Partial
// slot [bid][seg] holds a 256x256 bf16 tile-local contribution.
// Tile tc's contributors: j in [56tc/36, (56tc+55)/36]; slot = 0 if tc is
// block j's FIRST tile (floor(36j/56)==tc) else 1.
static __device__ __forceinline__ void qkv_gather(const short* __restrict__ Pp,
                                                  int tr, int tc, int s, int col0,
                                                  float* x, float* y) {
  const int j0 = (56 * tc) / 36, j1 = (56 * tc + 55) / 36;
  const size_t off = (size_t)(s & 255) * 256 + (col0 & 255);
#pragma unroll 1
  for (int j = j0; j <= j1; ++j) {
    const int slot = ((36 * j) / 56 == tc) ? 0 : 1;
    const short* p = Pp + ((size_t)((tr + 8 * j) * 2 + slot)) * 65536 + off;
    const bf16x8 lo = *(const bf16x8*)p;
    const bf16x8 hi = *(const bf16x8*)(p + 64);
#pragma unroll
    for (int q = 0; q < 8; ++q) { x[q] += bf2f(lo[q]); y[q] += bf2f(hi[q]); }
  }
}

// RoPE from QKV partials + bias -> bf16 qkvp (q,k regions). Q heads (h<28)
// pre-scaled by SCALE*LOG2E (exp2-domain scores).
__global__ void __launch_bounds__(256) rope_apply3(const short* __restrict__ Pp,
                                                   const float* __restrict__ bq,
                                                   const float* __restrict__ bk,
                                                   const float* __restrict__ ctab,
                                                   const float* __restrict__ stab,
                                                   short* __restrict__ qkvp) {
  const int idx = blockIdx.x * 256 + threadIdx.x;  // 2048*32*8
  const int c = idx & 7;
  const int h = (idx >> 3) & 31;
  const int s = idx >> 8;
  const int col0 = h * 128 + c * 8;
  float x[8] = {}, y[8] = {};
  qkv_gather(Pp, s >> 8, col0 >> 8, s, col0, x, y);
  const float qs = (h < 28) ? (0.08838834764831845f * LOG2E) : 1.0f;
  const float* bl = (h < 28) ? (bq + col0) : (bk + col0 - 3584);
  const float* cp = ctab + s * 64 + c * 8;
  const float* sp = stab + s * 64 + c * 8;
  bf16x8 lo2, hi2;
#pragma unroll
  for (int j = 0; j < 8; ++j) {
    const float xv = x[j] + bl[j], yv = y[j] + bl[j + 64];
    const float cv = cp[j], sv = sp[j];
    lo2[j] = f2bf((xv * cv - yv * sv) * qs);
    hi2[j] = f2bf((yv * cv + xv * sv) * qs);
  }
  short* dst = qkvp + (size_t)s * 4608 + col0;
  *(bf16x8*)dst = lo2;
  *(bf16x8*)(dst + 64) = hi2;
}

// V region from QKV partials + bias -> V^T bf16 [4][128][2048]
__global__ void __launch_bounds__(256) v_transpose3(const short* __restrict__ Pp,
                                                    const float* __restrict__ bv,
                                                    short* __restrict__ vtb) {
  __shared__ short t[64 * 48];
  const int dt = blockIdx.x, st = blockIdx.y, kv = blockIdx.z;
  const int tid = threadIdx.x;
  {
    const int r = tid >> 2, c8 = tid & 3;
    const int s = st * 64 + r;
    const int col0 = 4096 + kv * 128 + dt * 32 + c8 * 8;
    float x[8] = {}, ydummy[8] = {};
    // reuse gather for lo-half only: hi-half (col0+64) also needed; gather
    // gives both at col0 and col0+64 (same tile since 128B-aligned region).
    qkv_gather(Pp, s >> 8, col0 >> 8, s, col0, x, ydummy);
    const float* bp = bv + kv * 128 + dt * 32 + c8 * 8;
    // x = cols col0..+7; ydummy = cols col0+64..+71 -> belongs to c8+8 slot?
    // No: this thread owns only 8 cols; write x only.
#pragma unroll
    for (int j = 0; j < 8; ++j) t[r * 48 + c8 * 8 + j] = f2bf(x[j] + bp[j]);
  }
  __syncthreads();
  {
    const int d = tid >> 3, c = tid & 7;
    bf16x8 v;
#pragma unroll
    for (int i = 0; i < 8; ++i) v[i] = t[(c * 8 + i) * 48 + d];
    *(bf16x8*)(vtb + ((size_t)kv * 128 + dt * 32 + d) * 2048 + st * 64 + c * 8) = v;
  }
}

// O-proj reduce: out = p(seg half0) + p(seg half1), f32.
__global__ void __launch_bounds__(256) o_reduce(const short* __restrict__ Pp,
                                                float* __restrict__ out) {
  const int idx = blockIdx.x * 256 + threadIdx.x;  // 2048*448
  const int s = idx / 448;
  const int col0 = (idx % 448) * 8;
  const int tr = s >> 8, tc = col0 >> 8;
  const size_t off = (size_t)(s & 255) * 256 + (col0 & 255);
  const short* pA = Pp + ((size_t)((tr + 8 * (2 * tc)) * 2)) * 65536 + off;
  const short* pB = Pp + ((size_t)((tr + 8 * (2 * tc + 1)) * 2)) * 65536 + off;
  const bf16x8 a = *(const bf16x8*)pA;
  const bf16x8 b = *(const bf16x8*)pB;
  f32x4 o1, o2;
#pragma unroll
  for (int q = 0; q < 4; ++q) {
    o1[q] = bf2f(a[q]) + bf2f(b[q]);
    o2[q] = bf2f(a[q + 4]) + bf2f(b[q + 4]);
  }
  float* dst = out + (size_t)s * 3584 + col0;
  *(f32x4*)dst = o1;
  *(f32x4*)(dst + 4) = o2;
}

// ----- stream-K 8-phase bf16 GEMM -> bf16 PARTIAL tiles (no atomics) -------
// A[2048,K]*B[N,K]^T. 224 blocks: bid = row(M-tile, &7 -> XCD) + 8*j.
// Row-local k-units: unit u -> (tile T=u/56, ktile u%56). Block j owns
// [j*UNITS, j*UNITS+UNITS) (UNITS=36 QKV crosses <=1 boundary; 28 O never).
// Phase/sync/vmcnt schedule identical to r7 (ledger-verified). Epilogue:
// plain coalesced bf16 stores to Pp[bid][seg][256x256]; boundary parity is
// even -> mid-epilogue only at post-P8 point. Stores inflate vmcnt ->
// subsequent counted waits only get stronger.
template <int UNITS>
__global__ void __launch_bounds__(512, 2)
gemm_skp(const short* __restrict__ A, const short* __restrict__ B,
         short* __restrict__ Pp, int K) {
  __shared__ short As[2][256 * 64];
  __shared__ short Bs[2][256 * 64];
  const int bid = (int)blockIdx.x;
  const int row = bid & 7, jj = bid >> 3;
  const int u0 = jj * UNITS;
  const int T0 = u0 / 56;
  const int Tend = (u0 + UNITS - 1) / 56;
  const int kb1 = 56 * (T0 + 1);
  const int tm = row * 256;
  const int tid = (int)threadIdx.x;
  const int wave = tid >> 6, lane = tid & 63;
  const int l15 = lane & 15, g = lane >> 4;
  const int wm = wave >> 2, wn = wave & 3;

  f32x4 acc[2][4][2][2] = {};  // [rh][mq][ch][nq]
  bf16x8 af[4][2], b0[2][2], b1[2][2];

#define STG_A(b, uu, h)                                                         \
  { const int kt_ = (uu) % 56;                                                  \
    _Pragma("unroll") for (int jq = 0; jq < 2; ++jq) {                          \
      const int lr = (h) * 128 + jq * 64 + (tid >> 3);                          \
      const int wmm = (lr >> 6) & 1;                                            \
      const int rr = lr & 63;                                                   \
      const int grow = wmm * 128 + (h) * 64 + rr;                               \
      const int sc = (tid & 7) ^ (rr & 7);                                      \
      gll16(A + (size_t)(tm + grow) * K + (size_t)kt_ * 64 + sc * 8,            \
            &As[b][((h) * 128 + jq * 64 + wave * 8) * 64]);                     \
    } }
#define STG_B(b, uu, h)                                                         \
  { const int T_ = (uu) / 56;                                                   \
    const int kt_ = (uu) - T_ * 56;                                             \
    const int tn_ = T_ * 256;                                                   \
    _Pragma("unroll") for (int jq = 0; jq < 2; ++jq) {                          \
      const int lr = (h) * 128 + jq * 64 + (tid >> 3);                          \
      const int wnn = (lr >> 5) & 3;                                            \
      const int rr = lr & 31;                                                   \
      const int gcol = wnn * 64 + (h) * 32 + rr;                                \
      const int sc = (tid & 7) ^ (rr & 7);                                      \
      gll16(B + (size_t)(tn_ + gcol) * K + (size_t)kt_ * 64 + sc * 8,           \
            &Bs[b][((h) * 128 + jq * 64 + wave * 8) * 64]);                     \
    } }
#define LDA(buf, rh)                                                            \
  { _Pragma("unroll") for (int mq = 0; mq < 4; ++mq)                            \
      _Pragma("unroll") for (int ks = 0; ks < 2; ++ks) {                        \
        const int lr = (rh) * 128 + wm * 64 + mq * 16 + l15;                    \
        af[mq][ks] =                                                            \
            *(const bf16x8*)(&As[buf][lr * 64 + (((ks * 4 + g) ^ (lr & 7)) * 8)]); \
      } }
#define LDB(buf, ch, ARR)                                                       \
  { _Pragma("unroll") for (int nq = 0; nq < 2; ++nq)                            \
      _Pragma("unroll") for (int ks = 0; ks < 2; ++ks) {                        \
        const int lr = (ch) * 128 + wn * 32 + nq * 16 + l15;                    \
        ARR[nq][ks] =                                                           \
            *(const bf16x8*)(&Bs[buf][lr * 64 + (((ks * 4 + g) ^ (lr & 7)) * 8)]); \
      } }
#define VMW() { asm volatile("s_waitcnt vmcnt(4)" ::: "memory"); }
#define PH(RH, CH, BARR, TAILBLK)                                               \
  {                                                                             \
    __builtin_amdgcn_s_barrier();                                               \
    asm volatile("s_waitcnt lgkmcnt(0)" ::: "memory");                          \
    __builtin_amdgcn_sched_barrier(0);                                          \
    __builtin_amdgcn_s_setprio(1);                                              \
    _Pragma("unroll") for (int mq = 0; mq < 4; ++mq)                            \
      _Pragma("unroll") for (int nq = 0; nq < 2; ++nq) {                        \
        acc[RH][mq][CH][nq] = MFMA16(af[mq][0], BARR[nq][0], acc[RH][mq][CH][nq]); \
        acc[RH][mq][CH][nq] = MFMA16(af[mq][1], BARR[nq][1], acc[RH][mq][CH][nq]); \
      }                                                                         \
    __builtin_amdgcn_s_setprio(0);                                              \
    TAILBLK;                                                                    \
    __builtin_amdgcn_sched_barrier(0);                                          \
  }
#define PEPI(seg)                                                               \
  { short* pb = Pp + ((size_t)bid * 2 + (seg)) * 65536;                         \
    _Pragma("unroll") for (int rh = 0; rh < 2; ++rh)                            \
    _Pragma("unroll") for (int mq = 0; mq < 4; ++mq)                            \
    _Pragma("unroll") for (int ch = 0; ch < 2; ++ch)                            \
    _Pragma("unroll") for (int nq = 0; nq < 2; ++nq) {                          \
      const int colL = wn * 64 + ch * 32 + nq * 16 + l15;                       \
      const int rowL = wm * 128 + rh * 64 + mq * 16 + g * 4;                    \
      _Pragma("unroll") for (int r = 0; r < 4; ++r)                             \
        pb[(rowL + r) * 256 + colL] = f2bf(acc[rh][mq][ch][nq][r]);             \
    } }
#define RSTACC()                                                                \
  { _Pragma("unroll") for (int rh = 0; rh < 2; ++rh)                            \
    _Pragma("unroll") for (int mq = 0; mq < 4; ++mq)                            \
    _Pragma("unroll") for (int ch = 0; ch < 2; ++ch)                            \
    _Pragma("unroll") for (int nq = 0; nq < 2; ++nq)                            \
      acc[rh][mq][ch][nq] = f32x4{0.f, 0.f, 0.f, 0.f}; }

  // prologue: stage units u0 (buf0), u0+1 (buf1); drain u0; read P1 frags.
  STG_A(0, u0, 0); STG_A(0, u0, 1); STG_B(0, u0, 0); STG_B(0, u0, 1);
  STG_A(1, u0 + 1, 0); STG_A(1, u0 + 1, 1); STG_B(1, u0 + 1, 0); STG_B(1, u0 + 1, 1);
  asm volatile("s_waitcnt vmcnt(8)" ::: "memory");
  __builtin_amdgcn_s_barrier();
  LDA(0, 0); LDB(0, 0, b0);

#pragma unroll 1
  for (int i = 0; i < UNITS / 2; ++i) {
    const int uu2 = u0 + 2 * i + 2, uu3 = uu2 + 1;
    const bool more = (i < UNITS / 2 - 1);
    PH(0, 0, b0, { LDB(0, 1, b1); });
    PH(0, 1, b1, { if (more) STG_A(0, uu2, 0); LDA(0, 1); });
    PH(1, 1, b1, { if (more) { STG_B(0, uu2, 1); VMW(); }
                   else { asm volatile("s_waitcnt vmcnt(0)" ::: "memory"); } });
    PH(1, 0, b0, { if (more) { STG_A(0, uu2, 1); STG_B(0, uu2, 0); }
                   LDA(1, 0); LDB(1, 0, b0); });
    PH(0, 0, b0, { LDB(1, 1, b1); });
    PH(0, 1, b1, { if (more) STG_A(1, uu3, 0); LDA(1, 1); });
    PH(1, 1, b1, { if (more) { STG_B(1, uu3, 1); VMW(); } });
    PH(1, 0, b0, { if (more) { STG_A(1, uu3, 1); STG_B(1, uu3, 0);
                               LDA(0, 0); LDB(0, 0, b0); } });
    // tile boundary (even parity -> only possible here); never on last iter.
    if (Tend > T0 && (u0 + 2 * i + 2 == kb1)) { PEPI(0); RSTACC(); }
  }
  PEPI((Tend > T0) ? 1 : 0);
#undef STG_A
#undef STG_B
#undef LDA
#undef LDB
#undef VMW
#undef PH
#undef PEPI
#undef RSTACC
}

// ---------------- flash attention, 2-phase pipelined, paired q-tiles --------
__global__ void __launch_bounds__(256) attn_kernel(const short* __restrict__ qkv,
                                                   const short* __restrict__ vtb,
                                                   short* __restrict__ outb) {
  const int lid = (int)blockIdx.x + ((int)blockIdx.y << 4);
  const int kvh = (lid & 7) >> 1;
  const int u = ((lid >> 3) << 1) + (lid & 1);  // 0..111 within kv group
  const int head = kvh * 7 + (u >> 4);
  const int qtA = u & 15, qtB = 31 - qtA;

  const int tid = threadIdx.x;
  const int lane = tid & 63, wave = tid >> 6;
  const int l15 = lane & 15, g = lane >> 4;

  __shared__ short Ks[2][64 * 128];
  __shared__ short Vs[2][128 * 64];
  __shared__ short Ps[4][16 * 64];

  const short* kbase = qkv + 3584 + kvh * 128;
  const short* vbase = vtb + (size_t)kvh * 128 * 2048;
  const float NINF = -__builtin_inff();

  bf16x8 qf[4];
  f32x4 o[8];
  float mrun[4], lrun[4];

#define LOADQ(qt)                                                                  \
  {                                                                                \
    const short* qptr =                                                            \
        qkv + (size_t)((qt)*64 + wave * 16 + l15) * 4608 + head * 128 + g * 8;     \
    _Pragma("unroll") for (int ds = 0; ds < 4; ++ds) qf[ds] =                      \
        *(const bf16x8*)(qptr + ds * 32);                                          \
  }
#define RESET()                                                                    \
  {                                                                                \
    _Pragma("unroll") for (int nd = 0; nd < 8; ++nd) o[nd] = f32x4{0.f,0.f,0.f,0.f}; \
    _Pragma("unroll") for (int r = 0; r < 4; ++r) { mrun[r] = NINF; lrun[r] = 0.f; } \
  }
#define STAGE(kv, b)                                                               \
  {                                                                                \
    _Pragma("unroll") for (int it = 0; it < 4; ++it) {                             \
      const int chunk = it * 256 + tid;                                            \
      const int row = chunk >> 4, sc = (chunk & 15) ^ (row & 7);                   \
      gll16(kbase + (size_t)((kv)*64 + row) * 4608 + sc * 8,                       \
            &Ks[b][(it * 256 + wave * 64) * 8]);                                   \
    }                                                                              \
    _Pragma("unroll") for (int it = 0; it < 4; ++it) {                             \
      const int chunk = it * 256 + tid;                                            \
      const int row = chunk >> 3, sc = (chunk & 7) ^ (row & 7);                    \
      gll16(vbase + (size_t)row * 2048 + (kv)*64 + sc * 8,                         \
            &Vs[b][(it * 256 + wave * 64) * 8]);                                   \
    }                                                                              \
  }

  RESET();
  LOADQ(qtA);
  STAGE(0, 0);
  __syncthreads();
  int cur = 0;

  for (int s = 0; s < 33; ++s) {
    if (s < 32) {
      const int sn = s + 1;
      const int kvn = (sn <= qtA) ? sn : sn - qtA - 1;
      STAGE(kvn, cur ^ 1);
    }
    const int qt = (s <= qtA) ? qtA : qtB;
    const int kv = (s <= qtA) ? s : s - qtA - 1;
    const bool diag = (s == qtA) || (s == 32);

    f32x4 sf[4] = {};
    __builtin_amdgcn_s_setprio(1);
#pragma unroll
    for (int n = 0; n < 4; ++n) {
      const int krow = n * 16 + l15;
#pragma unroll
      for (int ds = 0; ds < 4; ++ds) {
        const int c = (ds * 4 + g) ^ (krow & 7);
        const bf16x8 kf = *(const bf16x8*)(&Ks[cur][krow * 128 + c * 8]);
        sf[n] = MFMA16(qf[ds], kf, sf[n]);
      }
    }
    __builtin_amdgcn_s_setprio(0);

    if (diag) {
#pragma unroll
      for (int r = 0; r < 4; ++r) {
        const int qr = qt * 64 + wave * 16 + g * 4 + r;
#pragma unroll
        for (int n = 0; n < 4; ++n)
          if (kv * 64 + n * 16 + l15 > qr) sf[n][r] = NINF;
      }
    }
    float pmax[4];
#pragma unroll
    for (int r = 0; r < 4; ++r)
      pmax[r] = fmaxf(fmaxf(sf[0][r], sf[1][r]), fmaxf(sf[2][r], sf[3][r]));
    const bool need = (pmax[0] > mrun[0] + 8.f) || (pmax[1] > mrun[1] + 8.f) ||
                      (pmax[2] > mrun[2] + 8.f) || (pmax[3] > mrun[3] + 8.f);
    if (__any(need)) {
#pragma unroll
      for (int r = 0; r < 4; ++r) {
        float mx = pmax[r];
        mx = fmaxf(mx, __shfl_xor(mx, 1));
        mx = fmaxf(mx, __shfl_xor(mx, 2));
        mx = fmaxf(mx, __shfl_xor(mx, 4));
        mx = fmaxf(mx, __shfl_xor(mx, 8));
        const float mnew = fmaxf(mrun[r], mx);
        const float alpha = exp2f(mrun[r] - mnew);
        mrun[r] = mnew;
        lrun[r] *= alpha;
#pragma unroll
        for (int nd = 0; nd < 8; ++nd) o[nd][r] *= alpha;
      }
    }
#pragma unroll
    for (int n = 0; n < 4; ++n) {
#pragma unroll
      for (int r = 0; r < 4; ++r) {
        const float p = exp2f(sf[n][r] - mrun[r]);
        lrun[r] += p;
        const int prow = g * 4 + r, key = n * 16 + l15;
        const int cp = (key >> 3) ^ (prow & 7);
        Ps[wave][prow * 64 + cp * 8 + (key & 7)] = f2bf(p);
      }
    }
    bf16x8 pf[2];
#pragma unroll
    for (int ksl = 0; ksl < 2; ++ksl) {
      const int c = (ksl * 4 + g) ^ (l15 & 7);
      pf[ksl] = *(const bf16x8*)(&Ps[wave][l15 * 64 + c * 8]);
    }
    __builtin_amdgcn_s_setprio(1);
#pragma unroll
    for (int nd = 0; nd < 8; ++nd) {
      const int vrow = nd * 16 + l15;
#pragma unroll
      for (int ksl = 0; ksl < 2; ++ksl) {
        const int c = (ksl * 4 + g) ^ (vrow & 7);
        const bf16x8 vf = *(const bf16x8*)(&Vs[cur][vrow * 64 + c * 8]);
        o[nd] = MFMA16(pf[ksl], vf, o[nd]);
      }
    }
    __builtin_amdgcn_s_setprio(0);

    if (diag) {
      float inv[4];
#pragma unroll
      for (int r = 0; r < 4; ++r) {
        float sum = lrun[r];
        sum += __shfl_xor(sum, 1);
        sum += __shfl_xor(sum, 2);
        sum += __shfl_xor(sum, 4);
        sum += __shfl_xor(sum, 8);
        inv[r] = 1.0f / sum;
      }
#pragma unroll
      for (int nd = 0; nd < 8; ++nd) {
#pragma unroll
        for (int r = 0; r < 4; ++r) {
          const int qr = qt * 64 + wave * 16 + g * 4 + r;
          outb[(size_t)qr * 3584 + head * 128 + nd * 16 + l15] = f2bf(o[nd][r] * inv[r]);
        }
      }
      if (s == qtA) {
        RESET();
        LOADQ(qtB);
      }
    }
    __syncthreads();
    cur ^= 1;
  }
#undef LOADQ
#undef RESET
#undef STAGE
}

extern "C" void kernel_launch(void* const* d_in, const int* in_sizes, int n_in,
                              void* d_out, int out_size, void* d_ws, size_t ws_size,
                              hipStream_t stream) {
  const float* h  = (const float*)d_in[0];
  const int* pos  = (const int*)d_in[1];
  const float* Wq = (const float*)d_in[2];
  const float* bq = (const float*)d_in[3];
  const float* Wk = (const float*)d_in[4];
  const float* bk = (const float*)d_in[5];
  const float* Wv = (const float*)d_in[6];
  const float* bv = (const float*)d_in[7];
  const float* Wo = (const float*)d_in[8];
  float* out = (float*)d_out;

  char* w = (char*)d_ws;
  short* hbf  = (short*)w; w += (size_t)2048 * 3584 * 2;
  short* Wall = (short*)w; w += (size_t)4608 * 3584 * 2;
  short* qkvp = (short*)w; w += (size_t)2048 * 4608 * 2;
  float* ctab = (float*)w; w += 2048 * 64 * 4;
  float* stab = (float*)w; w += 2048 * 64 * 4;
  short* vtb  = (short*)w; w += (size_t)4 * 128 * 2048 * 2;
  short* Pp   = (short*)w; w += (size_t)224 * 2 * 65536 * 2;  // 58.7 MB partials
  short* attnb = hbf;   // hbf dead after QKV GEMM
  short* Wob = Wall;    // Wall dead after QKV GEMM

  cvt_kernel<<<2048, 256, 0, stream>>>(h, hbf, (long long)2048 * 3584);
  cvt_kernel<<<2048, 256, 0, stream>>>(Wq, Wall, (long long)3584 * 3584);
  cvt_kernel<<<512, 256, 0, stream>>>(Wk, Wall + (size_t)3584 * 3584, (long long)512 * 3584);
  cvt_kernel<<<512, 256, 0, stream>>>(Wv, Wall + (size_t)4096 * 3584, (long long)512 * 3584);
  rope_table<<<2048, 64, 0, stream>>>(pos, ctab, stab);

  // QKV: 8 rows x (18 tiles x 56 kt = 1008 units) = 8 x 28 blocks x 36 units
  gemm_skp<36><<<224, 512, 0, stream>>>(hbf, Wall, Pp, 3584);

  cvt_kernel<<<2048, 256, 0, stream>>>(Wo, Wob, (long long)3584 * 3584);
  rope_apply3<<<2048, 256, 0, stream>>>(Pp, bq, bk, ctab, stab, qkvp);
  v_transpose3<<<dim3(4, 32, 4), 256, 0, stream>>>(Pp, bv, vtb);

  attn_kernel<<<dim3(16, 28), 256, 0, stream>>>(qkvp, vtb, attnb);

  // O-proj: 8 rows x (14 tiles x 56 kt = 784 units) = 8 x 28 blocks x 28 units
  gemm_skp<28><<<224, 512, 0, stream>>>(attnb, Wob, Pp, 3584);
  o_reduce<<<3584, 256, 0, stream>>>(Pp, out);
}

// Round 10
// 321.984 us; speedup vs baseline: 1.6095x; 1.6095x over previous
//
#include <hip/hip_runtime.h>

typedef __attribute__((ext_vector_type(4))) float f32x4;
typedef __attribute__((ext_vector_type(8))) short bf16x8;
typedef __attribute__((ext_vector_type(4))) short bf16x4;

#define MFMA16(a, b, c) __builtin_amdgcn_mfma_f32_16x16x32_bf16((a), (b), (c), 0, 0, 0)
#define LOG2E 1.44269504088896340736f

static __device__ __forceinline__ float bf2f(short u) {
  unsigned x = ((unsigned)(unsigned short)u) << 16;
  return __builtin_bit_cast(float, x);
}
static __device__ __forceinline__ short f2bf(float f) {
  unsigned u = __builtin_bit_cast(unsigned, f);
  u += 0x7fffu + ((u >> 16) & 1u);
  return (short)(u >> 16);
}
// global -> LDS direct DMA, 16B per lane (guide §5); source pre-swizzled.
static __device__ __forceinline__ void gll16(const void* g, void* l) {
  __builtin_amdgcn_global_load_lds(
      (const __attribute__((address_space(1))) unsigned*)(unsigned long long)g,
      (__attribute__((address_space(3))) unsigned*)(unsigned)(unsigned long long)l,
      16, 0, 0);
}
// Permuted-partial index: short offset of tile element (row,col) in a slot.
// Writer: wave w stores bf16x4 (r=0..3) at (q*8+w)*256 + lane*4 shorts.
static __device__ __forceinline__ int pidx(int row, int col) {
  const int q = ((((row >> 6) & 1) * 4 + ((row >> 4) & 3)) * 2 + ((col >> 5) & 1)) * 2 +
                ((col >> 4) & 1);
  const int w = ((row >> 7) << 2) + (col >> 6);
  return (q * 8 + w) * 256 + (((row >> 2) & 3) * 16 + (col & 15)) * 4 + (row & 3);
}

// ------- merged f32 -> bf16 conversion: h, Wq, Wk, Wv in one launch --------
__global__ void __launch_bounds__(256) cvt4(const float* __restrict__ h,
                                            const float* __restrict__ wq,
                                            const float* __restrict__ wk,
                                            const float* __restrict__ wv,
                                            short* __restrict__ hbf,
                                            short* __restrict__ wall) {
  const long long C0 = 917504, C1 = 1605632, C2 = 229376;  // 8-elem chunks
  long long ch = (long long)blockIdx.x * 256 + threadIdx.x;
  const long long stride = (long long)gridDim.x * 256;
  const long long total = C0 + C1 + 2 * C2;
  for (; ch < total; ch += stride) {
    const float* s;
    short* d;
    long long off;
    if (ch < C0) { s = h; d = hbf; off = ch; }
    else if (ch < C0 + C1) { s = wq; d = wall; off = ch - C0; }
    else if (ch < C0 + C1 + C2) { s = wk; d = wall + (size_t)3584 * 3584; off = ch - C0 - C1; }
    else { s = wv; d = wall + (size_t)4096 * 3584; off = ch - C0 - C1 - C2; }
    const long long i = off * 8;
    f32x4 a = *(const f32x4*)(s + i);
    f32x4 b = *(const f32x4*)(s + i + 4);
    bf16x8 o;
    o[0] = f2bf(a[0]); o[1] = f2bf(a[1]); o[2] = f2bf(a[2]); o[3] = f2bf(a[3]);
    o[4] = f2bf(b[0]); o[5] = f2bf(b[1]); o[6] = f2bf(b[2]); o[7] = f2bf(b[3]);
    *(bf16x8*)(d + i) = o;
  }
}

__global__ void __launch_bounds__(256) cvt_kernel(const float* __restrict__ src,
                                                  short* __restrict__ dst,
                                                  long long n) {
  long long i = ((long long)blockIdx.x * 256 + threadIdx.x) * 8;
  const long long stride = (long long)gridDim.x * 256 * 8;
  for (; i < n; i += stride) {
    f32x4 a = *(const f32x4*)(src + i);
    f32x4 b = *(const f32x4*)(src + i + 4);
    bf16x8 o;
    o[0] = f2bf(a[0]); o[1] = f2bf(a[1]); o[2] = f2bf(a[2]); o[3] = f2bf(a[3]);
    o[4] = f2bf(b[0]); o[5] = f2bf(b[1]); o[6] = f2bf(b[2]); o[7] = f2bf(b[3]);
    *(bf16x8*)(dst + i) = o;
  }
}

// ---------------- RoPE cos/sin table: [2048][64] ----------------
__global__ void rope_table(const int* __restrict__ pos, float* __restrict__ ctab,
                           float* __restrict__ stab) {
  const int s = blockIdx.x;
  const int i = threadIdx.x;  // 0..63
  const float p = (float)pos[s];
  const float ang = p * exp2f(-(float)i * 0.3114307588956902f);
  ctab[s * 64 + i] = cosf(ang);
  stab[s * 64 + i] = sinf(ang);
}

// RoPE from QKV permuted partials + bias -> bf16 qkvp (q,k regions).
// Q heads (h<28) pre-scaled by SCALE*LOG2E (exp2-domain scores).
__global__ void __launch_bounds__(256) rope_apply4(const short* __restrict__ Pp,
                                                   const float* __restrict__ bq,
                                                   const float* __restrict__ bk,
                                                   const float* __restrict__ ctab,
                                                   const float* __restrict__ stab,
                                                   short* __restrict__ qkvp) {
  const int idx = blockIdx.x * 256 + threadIdx.x;  // 2048*32*8
  const int c = idx & 7;
  const int h = (idx >> 3) & 31;
  const int s = idx >> 8;
  const int col0 = h * 128 + c * 8;
  const int tr = s >> 8, tc = col0 >> 8;
  const int xcd = ((tr >> 1) << 1) + (tc >= 9 ? 1 : 0);
  const int tcr = (tc >= 9) ? tc - 9 : tc;
  const int rt = (tr & 1) + (tcr << 1);
  const int j0 = (56 * rt) / 36, j1 = (56 * rt + 55) / 36;
  const int rowL = s & 255;
  const int iLo = pidx(rowL, col0 & 255);
  const int iHi = pidx(rowL, (col0 + 64) & 255);
  float x[8] = {}, y[8] = {};
#pragma unroll 1
  for (int j = j0; j <= j1; ++j) {
    const int seg = ((36 * j) / 56 == rt) ? 0 : 1;
    const short* pb = Pp + ((size_t)(((xcd * 28 + j) << 1) + seg)) * 65536;
#pragma unroll
    for (int t = 0; t < 8; ++t) {
      x[t] += bf2f(pb[iLo + t * 4]);
      y[t] += bf2f(pb[iHi + t * 4]);
    }
  }
  const float qs = (h < 28) ? (0.08838834764831845f * LOG2E) : 1.0f;
  const float* bl = (h < 28) ? (bq + col0) : (bk + col0 - 3584);
  const float* cp = ctab + s * 64 + c * 8;
  const float* sp = stab + s * 64 + c * 8;
  bf16x8 lo2, hi2;
#pragma unroll
  for (int j = 0; j < 8; ++j) {
    const float xv = x[j] + bl[j], yv = y[j] + bl[j + 64];
    const float cv = cp[j], sv = sp[j];
    lo2[j] = f2bf((xv * cv - yv * sv) * qs);
    hi2[j] = f2bf((yv * cv + xv * sv) * qs);
  }
  short* dst = qkvp + (size_t)s * 4608 + col0;
  *(bf16x8*)dst = lo2;
  *(bf16x8*)(dst + 64) = hi2;
}

// V region from permuted partials + bias -> V^T bf16 [4][128][2048]
__global__ void __launch_bounds__(256) v_transpose4(const short* __restrict__ Pp,
                                                    const float* __restrict__ bv,
                                                    short* __restrict__ vtb) {
  __shared__ short t[64 * 48];
  const int dt = blockIdx.x, st = blockIdx.y, kv = blockIdx.z;
  const int tid = threadIdx.x;
  {
    const int r = tid >> 2, c8 = tid & 3;
    const int s = st * 64 + r;
    const int col0 = 4096 + kv * 128 + dt * 32 + c8 * 8;
    const int tr = s >> 8, tc = col0 >> 8;  // tc in 16..17
    const int xcd = ((tr >> 1) << 1) + 1;
    const int tcr = tc - 9;
    const int rt = (tr & 1) + (tcr << 1);
    const int j0 = (56 * rt) / 36, j1 = (56 * rt + 55) / 36;
    const int iLo = pidx(s & 255, col0 & 255);
    float x[8] = {};
#pragma unroll 1
    for (int j = j0; j <= j1; ++j) {
      const int seg = ((36 * j) / 56 == rt) ? 0 : 1;
      const short* pb = Pp + ((size_t)(((xcd * 28 + j) << 1) + seg)) * 65536;
#pragma unroll
      for (int q = 0; q < 8; ++q) x[q] += bf2f(pb[iLo + q * 4]);
    }
    const float* bp = bv + kv * 128 + dt * 32 + c8 * 8;
#pragma unroll
    for (int j = 0; j < 8; ++j) t[r * 48 + c8 * 8 + j] = f2bf(x[j] + bp[j]);
  }
  __syncthreads();
  {
    const int d = tid >> 3, c = tid & 7;
    bf16x8 v;
#pragma unroll
    for (int i = 0; i < 8; ++i) v[i] = t[(c * 8 + i) * 48 + d];
    *(bf16x8*)(vtb + ((size_t)kv * 128 + dt * 32 + d) * 2048 + st * 64 + c * 8) = v;
  }
}

// O-proj reduce: out = seg(j=2rt) + seg(j=2rt+1), f32 (2x7 rect, NCH=7).
__global__ void __launch_bounds__(256) o_reduce2(const short* __restrict__ Pp,
                                                 float* __restrict__ out) {
  const int idx = blockIdx.x * 256 + threadIdx.x;  // 2048*448
  const int s = idx / 448;
  const int col0 = (idx % 448) * 8;
  const int tr = s >> 8, tc = col0 >> 8;  // tc 0..13
  const int xcd = ((tr >> 1) << 1) + (tc >= 7 ? 1 : 0);
  const int tcr = (tc >= 7) ? tc - 7 : tc;
  const int rt = (tr & 1) + (tcr << 1);
  const int iL = pidx(s & 255, col0 & 255);
  const short* pb0 = Pp + ((size_t)((xcd * 28 + 2 * rt) << 1)) * 65536;
  const short* pb1 = Pp + ((size_t)((xcd * 28 + 2 * rt + 1) << 1)) * 65536;
  f32x4 o1, o2;
#pragma unroll
  for (int q = 0; q < 4; ++q) {
    o1[q] = bf2f(pb0[iL + q * 4]) + bf2f(pb1[iL + q * 4]);
    o2[q] = bf2f(pb0[iL + (q + 4) * 4]) + bf2f(pb1[iL + (q + 4) * 4]);
  }
  float* dst = out + (size_t)s * 3584 + col0;
  *(f32x4*)dst = o1;
  *(f32x4*)(dst + 4) = o2;
}

// ---- stream-K 8-phase bf16 GEMM, XCD-rect-local, permuted bf16 partials ----
// A[2048,K]*B[N,K]^T. 224 blocks: xcd=bid&7 owns a 2x(NCH) tile rect
// (rowg=xcd>>1, colg=xcd&1); in-rect units u=(rt,kt)=(u/56,u%56); block
// jj=bid>>3 owns [36jj,36jj+36) (QKV) or [28jj,28jj+28) (O, tile-aligned).
// Phase/sync/vmcnt engine identical to r7 (ledger-verified). Epilogue:
// packed bf16x4 stores, 512B-contiguous per wave-instr (no partial lines),
// permuted slot layout (pidx inverse). Boundary parity even -> mid-epilogue
// only at post-P8 (r9-verified logic). Stores inflate vmcnt -> later counted
// waits only get stronger.
template <int UNITS, int NCH>
__global__ void __launch_bounds__(512, 2)
gemm_sk2(const short* __restrict__ A, const short* __restrict__ B,
         short* __restrict__ Pp, int K) {
  __shared__ short As[2][256 * 64];
  __shared__ short Bs[2][256 * 64];
  const int bid = (int)blockIdx.x;
  const int xcd = bid & 7, jj = bid >> 3;
  const int rowg = xcd >> 1, colg = xcd & 1;
  const int u0 = jj * UNITS;
  const int T0 = u0 / 56;
  const int Tend = (u0 + UNITS - 1) / 56;
  const int kb1 = 56 * (T0 + 1);
  const int tid = (int)threadIdx.x;
  const int wave = tid >> 6, lane = tid & 63;
  const int l15 = lane & 15, g = lane >> 4;
  const int wm = wave >> 2, wn = wave & 3;

  f32x4 acc[2][4][2][2] = {};  // [rh][mq][ch][nq]
  bf16x8 af[4][2], b0[2][2], b1[2][2];

#define STG_A(b, uu, h)                                                         \
  { const int rt_ = (uu) / 56, kt_ = (uu)-rt_ * 56;                             \
    const int tm_ = ((rowg << 1) + (rt_ & 1)) << 8;                             \
    _Pragma("unroll") for (int jq = 0; jq < 2; ++jq) {                          \
      const int lr = (h) * 128 + jq * 64 + (tid >> 3);                          \
      const int wmm = (lr >> 6) & 1;                                            \
      const int rr = lr & 63;                                                   \
      const int grow = wmm * 128 + (h) * 64 + rr;                               \
      const int sc = (tid & 7) ^ (rr & 7);                                      \
      gll16(A + (size_t)(tm_ + grow) * K + (size_t)kt_ * 64 + sc * 8,           \
            &As[b][((h) * 128 + jq * 64 + wave * 8) * 64]);                     \
    } }
#define STG_B(b, uu, h)                                                         \
  { const int rt_ = (uu) / 56, kt_ = (uu)-rt_ * 56;                             \
    const int tn_ = (colg * NCH + (rt_ >> 1)) << 8;                             \
    _Pragma("unroll") for (int jq = 0; jq < 2; ++jq) {                          \
      const int lr = (h) * 128 + jq * 64 + (tid >> 3);                          \
      const int wnn = (lr >> 5) & 3;                                            \
      const int rr = lr & 31;                                                   \
      const int gcol = wnn * 64 + (h) * 32 + rr;                                \
      const int sc = (tid & 7) ^ (rr & 7);                                      \
      gll16(B + (size_t)(tn_ + gcol) * K + (size_t)kt_ * 64 + sc * 8,           \
            &Bs[b][((h) * 128 + jq * 64 + wave * 8) * 64]);                     \
    } }
#define LDA(buf, rh)                                                            \
  { _Pragma("unroll") for (int mq = 0; mq < 4; ++mq)                            \
      _Pragma("unroll") for (int ks = 0; ks < 2; ++ks) {                        \
        const int lr = (rh) * 128 + wm * 64 + mq * 16 + l15;                    \
        af[mq][ks] =                                                            \
            *(const bf16x8*)(&As[buf][lr * 64 + (((ks * 4 + g) ^ (lr & 7)) * 8)]); \
      } }
#define LDB(buf, ch, ARR)                                                       \
  { _Pragma("unroll") for (int nq = 0; nq < 2; ++nq)                            \
      _Pragma("unroll") for (int ks = 0; ks < 2; ++ks) {                        \
        const int lr = (ch) * 128 + wn * 32 + nq * 16 + l15;                    \
        ARR[nq][ks] =                                                           \
            *(const bf16x8*)(&Bs[buf][lr * 64 + (((ks * 4 + g) ^ (lr & 7)) * 8)]); \
      } }
#define VMW() { asm volatile("s_waitcnt vmcnt(4)" ::: "memory"); }
#define PH(RH, CH, BARR, TAILBLK)                                               \
  {                                                                             \
    __builtin_amdgcn_s_barrier();                                               \
    asm volatile("s_waitcnt lgkmcnt(0)" ::: "memory");                          \
    __builtin_amdgcn_sched_barrier(0);                                          \
    __builtin_amdgcn_s_setprio(1);                                              \
    _Pragma("unroll") for (int mq = 0; mq < 4; ++mq)                            \
      _Pragma("unroll") for (int nq = 0; nq < 2; ++nq) {                        \
        acc[RH][mq][CH][nq] = MFMA16(af[mq][0], BARR[nq][0], acc[RH][mq][CH][nq]); \
        acc[RH][mq][CH][nq] = MFMA16(af[mq][1], BARR[nq][1], acc[RH][mq][CH][nq]); \
      }                                                                         \
    __builtin_amdgcn_s_setprio(0);                                              \
    TAILBLK;                                                                    \
    __builtin_amdgcn_sched_barrier(0);                                          \
  }
#define PEPI(seg)                                                               \
  { short* pb = Pp + ((size_t)(((xcd * 28 + jj) << 1) + (seg))) * 65536;        \
    _Pragma("unroll") for (int rh = 0; rh < 2; ++rh)                            \
    _Pragma("unroll") for (int mq = 0; mq < 4; ++mq)                            \
    _Pragma("unroll") for (int ch = 0; ch < 2; ++ch)                            \
    _Pragma("unroll") for (int nq = 0; nq < 2; ++nq) {                          \
      const int q_ = ((rh * 4 + mq) * 2 + ch) * 2 + nq;                         \
      bf16x4 pk;                                                                \
      pk[0] = f2bf(acc[rh][mq][ch][nq][0]);                                     \
      pk[1] = f2bf(acc[rh][mq][ch][nq][1]);                                     \
      pk[2] = f2bf(acc[rh][mq][ch][nq][2]);                                     \
      pk[3] = f2bf(acc[rh][mq][ch][nq][3]);                                     \
      *(bf16x4*)(pb + (q_ * 8 + wave) * 256 + lane * 4) = pk;                   \
    } }
#define RSTACC()                                                                \
  { _Pragma("unroll") for (int rh = 0; rh < 2; ++rh)                            \
    _Pragma("unroll") for (int mq = 0; mq < 4; ++mq)                            \
    _Pragma("unroll") for (int ch = 0; ch < 2; ++ch)                            \
    _Pragma("unroll") for (int nq = 0; nq < 2; ++nq)                            \
      acc[rh][mq][ch][nq] = f32x4{0.f, 0.f, 0.f, 0.f}; }

  // prologue: stage units u0 (buf0), u0+1 (buf1); drain u0; read P1 frags.
  STG_A(0, u0, 0); STG_A(0, u0, 1); STG_B(0, u0, 0); STG_B(0, u0, 1);
  STG_A(1, u0 + 1, 0); STG_A(1, u0 + 1, 1); STG_B(1, u0 + 1, 0); STG_B(1, u0 + 1, 1);
  asm volatile("s_waitcnt vmcnt(8)" ::: "memory");
  __builtin_amdgcn_s_barrier();
  LDA(0, 0); LDB(0, 0, b0);

#pragma unroll 1
  for (int i = 0; i < UNITS / 2; ++i) {
    const int uu2 = u0 + 2 * i + 2, uu3 = uu2 + 1;
    const bool more = (i < UNITS / 2 - 1);
    PH(0, 0, b0, { LDB(0, 1, b1); });
    PH(0, 1, b1, { if (more) STG_A(0, uu2, 0); LDA(0, 1); });
    PH(1, 1, b1, { if (more) { STG_B(0, uu2, 1); VMW(); }
                   else { asm volatile("s_waitcnt vmcnt(0)" ::: "memory"); } });
    PH(1, 0, b0, { if (more) { STG_A(0, uu2, 1); STG_B(0, uu2, 0); }
                   LDA(1, 0); LDB(1, 0, b0); });
    PH(0, 0, b0, { LDB(1, 1, b1); });
    PH(0, 1, b1, { if (more) STG_A(1, uu3, 0); LDA(1, 1); });
    PH(1, 1, b1, { if (more) { STG_B(1, uu3, 1); VMW(); } });
    PH(1, 0, b0, { if (more) { STG_A(1, uu3, 1); STG_B(1, uu3, 0);
                               LDA(0, 0); LDB(0, 0, b0); } });
    // tile boundary (even parity -> only possible here); never on last iter.
    if (Tend > T0 && (u0 + 2 * i + 2 == kb1)) { PEPI(0); RSTACC(); }
  }
  PEPI((Tend > T0) ? 1 : 0);
#undef STG_A
#undef STG_B
#undef LDA
#undef LDB
#undef VMW
#undef PH
#undef PEPI
#undef RSTACC
}

// ------- flash attention, 2-phase pipelined, 896 blocks (longest-first) -----
__global__ void __launch_bounds__(256) attn_kernel(const short* __restrict__ qkv,
                                                   const short* __restrict__ vtb,
                                                   short* __restrict__ outb) {
  const int lid = (int)blockIdx.x;   // 0..895, dispatched in order
  const int head = lid % 28;
  const int qt = 31 - lid / 28;      // longest q-tiles first
  const int kvh = head / 7;

  const int tid = threadIdx.x;
  const int lane = tid & 63, wave = tid >> 6;
  const int l15 = lane & 15, g = lane >> 4;

  __shared__ short Ks[2][64 * 128];
  __shared__ short Vs[2][128 * 64];
  __shared__ short Ps[4][16 * 64];

  const short* kbase = qkv + 3584 + kvh * 128;
  const short* vbase = vtb + (size_t)kvh * 128 * 2048;
  const float NINF = -__builtin_inff();

  bf16x8 qf[4];
  {
    const short* qptr = qkv + (size_t)(qt * 64 + wave * 16 + l15) * 4608 + head * 128 + g * 8;
#pragma unroll
    for (int ds = 0; ds < 4; ++ds) qf[ds] = *(const bf16x8*)(qptr + ds * 32);
  }
  f32x4 o[8] = {};
  float mrun[4] = {NINF, NINF, NINF, NINF};
  float lrun[4] = {0.f, 0.f, 0.f, 0.f};

#define STAGE(kv, b)                                                               \
  {                                                                                \
    _Pragma("unroll") for (int it = 0; it < 4; ++it) {                             \
      const int chunk = it * 256 + tid;                                            \
      const int row = chunk >> 4, sc = (chunk & 15) ^ (row & 7);                   \
      gll16(kbase + (size_t)((kv)*64 + row) * 4608 + sc * 8,                       \
            &Ks[b][(it * 256 + wave * 64) * 8]);                                   \
    }                                                                              \
    _Pragma("unroll") for (int it = 0; it < 4; ++it) {                             \
      const int chunk = it * 256 + tid;                                            \
      const int row = chunk >> 3, sc = (chunk & 7) ^ (row & 7);                    \
      gll16(vbase + (size_t)row * 2048 + (kv)*64 + sc * 8,                         \
            &Vs[b][(it * 256 + wave * 64) * 8]);                                   \
    }                                                                              \
  }

  STAGE(0, 0);
  __syncthreads();
  int cur = 0;

#pragma unroll 1
  for (int t = 0; t <= qt; ++t) {
    if (t < qt) STAGE(t + 1, cur ^ 1);
    const bool diag = (t == qt);

    f32x4 sf[4] = {};
    __builtin_amdgcn_s_setprio(1);
#pragma unroll
    for (int n = 0; n < 4; ++n) {
      const int krow = n * 16 + l15;
#pragma unroll
      for (int ds = 0; ds < 4; ++ds) {
        const int c = (ds * 4 + g) ^ (krow & 7);
        const bf16x8 kf = *(const bf16x8*)(&Ks[cur][krow * 128 + c * 8]);
        sf[n] = MFMA16(qf[ds], kf, sf[n]);
      }
    }
    __builtin_amdgcn_s_setprio(0);

    if (diag) {
#pragma unroll
      for (int r = 0; r < 4; ++r) {
        const int qr = qt * 64 + wave * 16 + g * 4 + r;
#pragma unroll
        for (int n = 0; n < 4; ++n)
          if (t * 64 + n * 16 + l15 > qr) sf[n][r] = NINF;
      }
    }
    float pmax[4];
#pragma unroll
    for (int r = 0; r < 4; ++r)
      pmax[r] = fmaxf(fmaxf(sf[0][r], sf[1][r]), fmaxf(sf[2][r], sf[3][r]));
    const bool need = (pmax[0] > mrun[0] + 8.f) || (pmax[1] > mrun[1] + 8.f) ||
                      (pmax[2] > mrun[2] + 8.f) || (pmax[3] > mrun[3] + 8.f);
    if (__any(need)) {
#pragma unroll
      for (int r = 0; r < 4; ++r) {
        float mx = pmax[r];
        mx = fmaxf(mx, __shfl_xor(mx, 1));
        mx = fmaxf(mx, __shfl_xor(mx, 2));
        mx = fmaxf(mx, __shfl_xor(mx, 4));
        mx = fmaxf(mx, __shfl_xor(mx, 8));
        const float mnew = fmaxf(mrun[r], mx);
        const float alpha = exp2f(mrun[r] - mnew);
        mrun[r] = mnew;
        lrun[r] *= alpha;
#pragma unroll
        for (int nd = 0; nd < 8; ++nd) o[nd][r] *= alpha;
      }
    }
#pragma unroll
    for (int n = 0; n < 4; ++n) {
#pragma unroll
      for (int r = 0; r < 4; ++r) {
        const float p = exp2f(sf[n][r] - mrun[r]);
        lrun[r] += p;
        const int prow = g * 4 + r, key = n * 16 + l15;
        const int cp = (key >> 3) ^ (prow & 7);
        Ps[wave][prow * 64 + cp * 8 + (key & 7)] = f2bf(p);
      }
    }
    bf16x8 pf[2];
#pragma unroll
    for (int ksl = 0; ksl < 2; ++ksl) {
      const int c = (ksl * 4 + g) ^ (l15 & 7);
      pf[ksl] = *(const bf16x8*)(&Ps[wave][l15 * 64 + c * 8]);
    }
    __builtin_amdgcn_s_setprio(1);
#pragma unroll
    for (int nd = 0; nd < 8; ++nd) {
      const int vrow = nd * 16 + l15;
#pragma unroll
      for (int ksl = 0; ksl < 2; ++ksl) {
        const int c = (ksl * 4 + g) ^ (vrow & 7);
        const bf16x8 vf = *(const bf16x8*)(&Vs[cur][vrow * 64 + c * 8]);
        o[nd] = MFMA16(pf[ksl], vf, o[nd]);
      }
    }
    __builtin_amdgcn_s_setprio(0);

    __syncthreads();
    cur ^= 1;
  }

  float inv[4];
#pragma unroll
  for (int r = 0; r < 4; ++r) {
    float sum = lrun[r];
    sum += __shfl_xor(sum, 1);
    sum += __shfl_xor(sum, 2);
    sum += __shfl_xor(sum, 4);
    sum += __shfl_xor(sum, 8);
    inv[r] = 1.0f / sum;
  }
#pragma unroll
  for (int nd = 0; nd < 8; ++nd) {
#pragma unroll
    for (int r = 0; r < 4; ++r) {
      const int qr = qt * 64 + wave * 16 + g * 4 + r;
      outb[(size_t)qr * 3584 + head * 128 + nd * 16 + l15] = f2bf(o[nd][r] * inv[r]);
    }
  }
#undef STAGE
}

extern "C" void kernel_launch(void* const* d_in, const int* in_sizes, int n_in,
                              void* d_out, int out_size, void* d_ws, size_t ws_size,
                              hipStream_t stream) {
  const float* h  = (const float*)d_in[0];
  const int* pos  = (const int*)d_in[1];
  const float* Wq = (const float*)d_in[2];
  const float* bq = (const float*)d_in[3];
  const float* Wk = (const float*)d_in[4];
  const float* bk = (const float*)d_in[5];
  const float* Wv = (const float*)d_in[6];
  const float* bv = (const float*)d_in[7];
  const float* Wo = (const float*)d_in[8];
  float* out = (float*)d_out;

  char* w = (char*)d_ws;
  short* hbf  = (short*)w; w += (size_t)2048 * 3584 * 2;
  short* Wall = (short*)w; w += (size_t)4608 * 3584 * 2;
  short* qkvp = (short*)w; w += (size_t)2048 * 4608 * 2;
  float* ctab = (float*)w; w += 2048 * 64 * 4;
  float* stab = (float*)w; w += 2048 * 64 * 4;
  short* vtb  = (short*)w; w += (size_t)4 * 128 * 2048 * 2;
  short* Pp   = (short*)w; w += (size_t)448 * 65536 * 2;  // 57.3 MB partials
  short* attnb = hbf;   // hbf dead after QKV GEMM
  short* Wob = Wall;    // Wall dead after QKV GEMM

  cvt4<<<2048, 256, 0, stream>>>(h, Wq, Wk, Wv, hbf, Wall);
  rope_table<<<2048, 64, 0, stream>>>(pos, ctab, stab);

  // QKV: per XCD 2x9 tile rect, 1008 units = 28 blocks x 36
  gemm_sk2<36, 9><<<224, 512, 0, stream>>>(hbf, Wall, Pp, 3584);

  cvt_kernel<<<2048, 256, 0, stream>>>(Wo, Wob, (long long)3584 * 3584);
  rope_apply4<<<2048, 256, 0, stream>>>(Pp, bq, bk, ctab, stab, qkvp);
  v_transpose4<<<dim3(4, 32, 4), 256, 0, stream>>>(Pp, bv, vtb);

  attn_kernel<<<896, 256, 0, stream>>>(qkvp, vtb, attnb);

  // O-proj: per XCD 2x7 rect, 784 units = 28 blocks x 28 (tile-aligned)
  gemm_sk2<28, 7><<<224, 512, 0, stream>>>(attnb, Wob, Pp, 3584);
  o_reduce2<<<3584, 256, 0, stream>>>(Pp, out);
}